// Round 3
// baseline (1094.911 us; speedup 1.0000x reference)
//
#include <hip/hip_runtime.h>
#include <hip/hip_bf16.h>

#define BUCKETS 32
#define BSZ 128            // tokens per bucket (4096/32)
#define DH 64
#define TEMPINV 1.3333333333333333f   // 1/0.75
#define SINK_ITERS 7
#define LOG_EPS 1e-6f
#define SCALE 0.03125f     // DIM^-0.5 = 1024^-0.5

// ---- bf16 helpers (bit-level, RNE rounding) ----
__device__ __forceinline__ void bf8_to_f32(const uint4 x, float* f) {
    f[0] = __uint_as_float(x.x << 16);
    f[1] = __uint_as_float(x.x & 0xffff0000u);
    f[2] = __uint_as_float(x.y << 16);
    f[3] = __uint_as_float(x.y & 0xffff0000u);
    f[4] = __uint_as_float(x.z << 16);
    f[5] = __uint_as_float(x.z & 0xffff0000u);
    f[6] = __uint_as_float(x.w << 16);
    f[7] = __uint_as_float(x.w & 0xffff0000u);
}

__device__ __forceinline__ unsigned f2bf(float f) {
    unsigned x = __float_as_uint(f);
    return (x + 0x7fffu + ((x >> 16) & 1u)) >> 16;   // RNE (no NaN in this data)
}

__device__ __forceinline__ uint4 packbf8(const float* f) {
    uint4 r;
    r.x = f2bf(f[0]) | (f2bf(f[1]) << 16);
    r.y = f2bf(f[2]) | (f2bf(f[3]) << 16);
    r.z = f2bf(f[4]) | (f2bf(f[5]) << 16);
    r.w = f2bf(f[6]) | (f2bf(f[7]) << 16);
    return r;
}

// ============================================================
// Kernel 1: routing matrix R (bh=64 blocks, 256 threads), fp32 in
// ============================================================
__global__ __launch_bounds__(256) void route_kernel(
    const float* __restrict__ kptr,
    const float* __restrict__ swptr,
    const float* __restrict__ gptr,
    float* __restrict__ Rout)
{
    const int b = blockIdx.x;          // bh index
    const int h = b & 15;              // head = bh % 16
    const int tid = threadIdx.x;

    __shared__ float bkr[BUCKETS][DH];        // 8 KB
    __shared__ float sw[DH][BUCKETS];         // 8 KB
    __shared__ float R[BUCKETS][BUCKETS + 1];

    // stage sort_w[h]: layout (h, d, v)
    for (int o = tid; o < DH * BUCKETS; o += 256)
        sw[o >> 5][o & 31] = swptr[h * DH * BUCKETS + o];

    // bucket K sums: thread owns (u, 8 columns), sums 128 rows
    {
        const float4* k4 = (const float4*)kptr + (size_t)b * 65536;
        const int u = tid >> 3, g = tid & 7;     // g: which 8-col group
        float s[8] = {0.f,0.f,0.f,0.f,0.f,0.f,0.f,0.f};
        for (int i = 0; i < BSZ; ++i) {
            float4 a = k4[u * 2048 + i * 16 + g * 2];
            float4 c = k4[u * 2048 + i * 16 + g * 2 + 1];
            s[0] += a.x; s[1] += a.y; s[2] += a.z; s[3] += a.w;
            s[4] += c.x; s[5] += c.y; s[6] += c.z; s[7] += c.w;
        }
        for (int j = 0; j < 8; ++j) bkr[u][g * 8 + j] = s[j];
    }
    __syncthreads();

    // logits
    for (int o = tid; o < BUCKETS * BUCKETS; o += 256) {
        const int uu = o >> 5, vv = o & 31;
        float dot = 0.f;
        for (int d = 0; d < DH; ++d) dot = fmaf(bkr[uu][d], sw[d][vv], dot);
        const float g = gptr[b * 1024 + o];
        R[uu][vv] = (logf(fmaxf(dot, 0.f) + LOG_EPS) + g) * TEMPINV;
    }
    __syncthreads();

    // Sinkhorn: row-lse (over v) then col-lse (over u), 7x
    for (int it = 0; it < SINK_ITERS; ++it) {
        if (tid < BUCKETS) {
            float m = -1e30f;
            for (int j = 0; j < BUCKETS; ++j) m = fmaxf(m, R[tid][j]);
            float s = 0.f;
            for (int j = 0; j < BUCKETS; ++j) s += expf(R[tid][j] - m);
            const float lse = m + logf(s);
            for (int j = 0; j < BUCKETS; ++j) R[tid][j] -= lse;
        }
        __syncthreads();
        if (tid < BUCKETS) {
            float m = -1e30f;
            for (int j = 0; j < BUCKETS; ++j) m = fmaxf(m, R[j][tid]);
            float s = 0.f;
            for (int j = 0; j < BUCKETS; ++j) s += expf(R[j][tid] - m);
            const float lse = m + logf(s);
            for (int j = 0; j < BUCKETS; ++j) R[j][tid] -= lse;
        }
        __syncthreads();
    }

    for (int o = tid; o < BUCKETS * BUCKETS; o += 256) {
        const int uu = o >> 5, vv = o & 31;
        Rout[b * 1024 + o] = (vv < uu) ? expf(R[uu][vv]) : 0.f;
    }
}

// ============================================================
// Kernel 2: reshuffle  k_re/v_re = tril(R,-1) · K/V  -> bf16 ws
//   grid (128 column-chunks of 64 floats, 64 bh), 256 threads
// ============================================================
__global__ __launch_bounds__(256) void reshuffle_kernel(
    const float* __restrict__ kptr,
    const float* __restrict__ vptr,
    const float* __restrict__ Rmat,
    uint4* __restrict__ kre,
    uint4* __restrict__ vre)
{
    const int cchunk = blockIdx.x;   // 0..127 : 64-float chunk of (t,d)=8192
    const int b = blockIdx.y;
    const int tid = threadIdx.x;

    __shared__ float lk[BUCKETS][64];      // 8 KB
    __shared__ float lv[BUCKETS][64];      // 8 KB
    __shared__ float lr[BUCKETS][BUCKETS + 1];

    const float4* kb4 = (const float4*)kptr + (size_t)b * 65536 + cchunk * 16;
    const float4* vb4 = (const float4*)vptr + (size_t)b * 65536 + cchunk * 16;

    for (int idx = tid; idx < 512; idx += 256) {
        const int v = idx >> 4, j = idx & 15;
        float4 t = kb4[v * 2048 + j];
        lk[v][j * 4 + 0] = t.x; lk[v][j * 4 + 1] = t.y;
        lk[v][j * 4 + 2] = t.z; lk[v][j * 4 + 3] = t.w;
        float4 s = vb4[v * 2048 + j];
        lv[v][j * 4 + 0] = s.x; lv[v][j * 4 + 1] = s.y;
        lv[v][j * 4 + 2] = s.z; lv[v][j * 4 + 3] = s.w;
    }
    for (int o = tid; o < 1024; o += 256)
        lr[o >> 5][o & 31] = Rmat[b * 1024 + o];
    __syncthreads();

    const int u = tid >> 3, c8 = tid & 7;
    float ka[8] = {0.f,0.f,0.f,0.f,0.f,0.f,0.f,0.f};
    float va[8] = {0.f,0.f,0.f,0.f,0.f,0.f,0.f,0.f};
    for (int vv = 0; vv < u; ++vv) {
        const float r = lr[u][vv];
        #pragma unroll
        for (int j = 0; j < 8; ++j) {
            ka[j] = fmaf(r, lk[vv][c8 * 8 + j], ka[j]);
            va[j] = fmaf(r, lv[vv][c8 * 8 + j], va[j]);
        }
    }
    const int oidx = b * 32768 + u * 1024 + cchunk * 8 + c8;
    kre[oidx] = packbf8(ka);
    vre[oidx] = packbf8(va);
}

// ============================================================
// Kernel 3: per-(bh,bucket) attention (grid 32 x 64, 128 thr)
//   MODE 1: load k_re/v_re from ws.  MODE 0: recompute (fallback)
//   OUTPUT: fp32 (float4 stores)
// ============================================================
template<int MODE>
__global__ __launch_bounds__(128) void attn_kernel(
    const float* __restrict__ qptr,
    const float* __restrict__ kptr,
    const float* __restrict__ vptr,
    const float* __restrict__ Rmat,
    const uint4* __restrict__ kre,
    const uint4* __restrict__ vre,
    float4* __restrict__ optr)
{
    const int u = blockIdx.x;
    const int b = blockIdx.y;
    const int tid = threadIdx.x;

    __shared__ uint4 sbk[2048];   // 32 KB : 256 rows x 64 bf16
    __shared__ uint4 sbv[2048];   // 32 KB

    const float4* k4 = (const float4*)kptr + (size_t)b * 65536;
    const float4* v4 = (const float4*)vptr + (size_t)b * 65536;
    const float4* q4 = (const float4*)qptr + (size_t)b * 65536;

    if (MODE == 1) {
        const uint4* kr = kre + (size_t)b * 32768 + u * 1024;
        const uint4* vr = vre + (size_t)b * 32768 + u * 1024;
        for (int o = tid; o < 1024; o += 128) {
            sbk[o] = kr[o];
            sbv[o] = vr[o];
            float4 a = k4[u * 2048 + 2 * o], c = k4[u * 2048 + 2 * o + 1];
            float f[8] = {a.x,a.y,a.z,a.w,c.x,c.y,c.z,c.w};
            sbk[1024 + o] = packbf8(f);
            float4 av = v4[u * 2048 + 2 * o], cv = v4[u * 2048 + 2 * o + 1];
            float g[8] = {av.x,av.y,av.z,av.w,cv.x,cv.y,cv.z,cv.w};
            sbv[1024 + o] = packbf8(g);
        }
    } else {
        const float* Rrow = Rmat + (b * BUCKETS + u) * BUCKETS;
        for (int o = tid; o < 1024; o += 128) {
            float ka[8] = {0.f,0.f,0.f,0.f,0.f,0.f,0.f,0.f};
            float va[8] = {0.f,0.f,0.f,0.f,0.f,0.f,0.f,0.f};
            for (int vv = 0; vv < u; ++vv) {
                const float r = Rrow[vv];
                float4 a = k4[vv * 2048 + 2 * o], c = k4[vv * 2048 + 2 * o + 1];
                ka[0] = fmaf(r, a.x, ka[0]); ka[1] = fmaf(r, a.y, ka[1]);
                ka[2] = fmaf(r, a.z, ka[2]); ka[3] = fmaf(r, a.w, ka[3]);
                ka[4] = fmaf(r, c.x, ka[4]); ka[5] = fmaf(r, c.y, ka[5]);
                ka[6] = fmaf(r, c.z, ka[6]); ka[7] = fmaf(r, c.w, ka[7]);
                float4 av = v4[vv * 2048 + 2 * o], cv = v4[vv * 2048 + 2 * o + 1];
                va[0] = fmaf(r, av.x, va[0]); va[1] = fmaf(r, av.y, va[1]);
                va[2] = fmaf(r, av.z, va[2]); va[3] = fmaf(r, av.w, va[3]);
                va[4] = fmaf(r, cv.x, va[4]); va[5] = fmaf(r, cv.y, va[5]);
                va[6] = fmaf(r, cv.z, va[6]); va[7] = fmaf(r, cv.w, va[7]);
            }
            sbk[o] = packbf8(ka);
            sbv[o] = packbf8(va);
            float4 a = k4[u * 2048 + 2 * o], c = k4[u * 2048 + 2 * o + 1];
            float f[8] = {a.x,a.y,a.z,a.w,c.x,c.y,c.z,c.w};
            sbk[1024 + o] = packbf8(f);
            float4 av = v4[u * 2048 + 2 * o], cv = v4[u * 2048 + 2 * o + 1];
            float g[8] = {av.x,av.y,av.z,av.w,cv.x,cv.y,cv.z,cv.w};
            sbv[1024 + o] = packbf8(g);
        }
    }
    __syncthreads();

    // Phase 2: one thread per query row
    const int i = tid;
    float qr[64];
    const float4* qrow = q4 + (u * 128 + i) * 16;
    for (int d4 = 0; d4 < 16; ++d4) {
        float4 t = qrow[d4];
        qr[d4 * 4 + 0] = t.x; qr[d4 * 4 + 1] = t.y;
        qr[d4 * 4 + 2] = t.z; qr[d4 * 4 + 3] = t.w;
    }

    float acc[64];
    for (int d = 0; d < 64; ++d) acc[d] = 0.f;
    float l = 0.f;

    for (int j = 0; j < 256; ++j) {
        float s = 0.f;
        for (int d8 = 0; d8 < 8; ++d8) {
            float f[8];
            bf8_to_f32(sbk[j * 8 + d8], f);
            for (int t = 0; t < 8; ++t) s = fmaf(qr[d8 * 8 + t], f[t], s);
        }
        // logits are O(1): shift-free softmax is exact up to fp32 rounding
        const float p = __expf(s * SCALE);
        l += p;
        for (int d8 = 0; d8 < 8; ++d8) {
            float f[8];
            bf8_to_f32(sbv[j * 8 + d8], f);
            for (int t = 0; t < 8; ++t)
                acc[d8 * 8 + t] = fmaf(p, f[t], acc[d8 * 8 + t]);
        }
    }

    const float inv = 1.f / l;
    float4* orow = optr + (size_t)b * 65536 + (u * 128 + i) * 16;
    for (int d4 = 0; d4 < 16; ++d4) {
        float4 t;
        t.x = acc[d4 * 4 + 0] * inv;
        t.y = acc[d4 * 4 + 1] * inv;
        t.z = acc[d4 * 4 + 2] * inv;
        t.w = acc[d4 * 4 + 3] * inv;
        orow[d4] = t;
    }
}

extern "C" void kernel_launch(void* const* d_in, const int* in_sizes, int n_in,
                              void* d_out, int out_size, void* d_ws, size_t ws_size,
                              hipStream_t stream) {
    const float* q  = (const float*)d_in[0];
    const float* k  = (const float*)d_in[1];
    const float* v  = (const float*)d_in[2];
    const float* sw = (const float*)d_in[3];
    const float* g  = (const float*)d_in[4];
    float4* out = (float4*)d_out;   // fp32 output

    // ws layout: R fp32 (256 KB) | k_re bf16 (33.5 MB) | v_re bf16 (33.5 MB)
    float* R   = (float*)d_ws;
    uint4* kre = (uint4*)((char*)d_ws + 262144);
    uint4* vre = (uint4*)((char*)d_ws + 262144 + 33554432);
    const bool big_ws = (ws_size >= (size_t)262144 + 2u * 33554432u);

    route_kernel<<<dim3(64), dim3(256), 0, stream>>>(k, sw, g, R);
    if (big_ws) {
        reshuffle_kernel<<<dim3(128, 64), dim3(256), 0, stream>>>(k, v, R, kre, vre);
        attn_kernel<1><<<dim3(32, 64), dim3(128), 0, stream>>>(q, k, v, R, kre, vre, out);
    } else {
        attn_kernel<0><<<dim3(32, 64), dim3(128), 0, stream>>>(q, k, v, R, kre, vre, out);
    }
}